// Round 6
// baseline (235.504 us; speedup 1.0000x reference)
//
#include <hip/hip_runtime.h>

#define H_ 56
#define W_ 56
#define HW_ 3136
#define CIN_ 256
#define COUT_ 256

typedef __attribute__((ext_vector_type(8))) short short8;
typedef __attribute__((ext_vector_type(4))) float f32x4;
typedef unsigned short ushort_t;

__device__ __forceinline__ int swz(int n) { return ((n ^ (n >> 3)) & 7) << 3; }

__device__ __forceinline__ ushort_t f2bf(float f) {
  union { float f; unsigned int i; } v; v.f = f;
  unsigned int b = v.i + (0x7fffu + ((v.i >> 16) & 1u));  // RNE
  return (ushort_t)(b >> 16);
}

__device__ __forceinline__ void cdir(int c, int& dx, int& dy) {
  if (c < 102)      { if (c < 51) { dx = 0; dy = 0; } else { dx = 1; dy = 0; } }
  else if (c < 153) { dx = -1; dy = 0; }
  else if (c < 204) { dx = 0;  dy = 1; }
  else              { dx = 0;  dy = -1; }
}

// ---- kernel 1: W -> bf16 pre-swizzled LDS images (8 tiles of 128m x 64k) + BN coefs ----
__global__ void prep_kernel(const float* __restrict__ wgt, const float* __restrict__ gamma,
                            const float* __restrict__ beta, const float* __restrict__ rmean,
                            const float* __restrict__ rvar,
                            ushort_t* __restrict__ wsw, float* __restrict__ bnp) {
  int idx = blockIdx.x * 256 + threadIdx.x;   // 65536
  int tile = idx >> 13;                       // bm*4 + s
  int within = idx & 8191;
  int m = within >> 6;
  int off = within & 63;
  int j = off >> 3, klo = off & 7;
  int koct = j ^ ((m ^ (m >> 3)) & 7);        // inverse of read-side XOR swizzle
  int bm = tile >> 2, s = tile & 3;
  int o = bm * 128 + m;
  int c = s * 64 + koct * 8 + klo;
  wsw[idx] = f2bf(wgt[o * CIN_ + c]);
  if (idx < COUT_) {
    float inv = gamma[idx] * rsqrtf(rvar[idx] + 1e-5f);
    bnp[2 * idx]     = inv;
    bnp[2 * idx + 1] = beta[idx] - rmean[idx] * inv;
  }
}

// ---- kernel 2: pipelined MFMA GEMM; dbl-buffered LDS, reg prefetch, 1 barrier/stage ----
__global__ __launch_bounds__(256, 2)
void shiftconv_mfma(const float* __restrict__ x, const ushort_t* __restrict__ wsw,
                    const float* __restrict__ bnp, float* __restrict__ out) {
  __shared__ ushort_t Ab[2][8192];   // [m=128][k=64] bf16, swizzled
  __shared__ ushort_t Bb[2][8192];   // [n=128][k=64] bf16, swizzled

  const int t    = threadIdx.x;
  const int bn   = blockIdx.x;       // 784
  const int bm   = blockIdx.y;       // 2
  const int lane = t & 63;
  const int wv   = t >> 6;
  const int wm   = wv >> 1;
  const int wn   = wv & 1;
  const int quad = lane >> 4;
  const int l15  = lane & 15;

  // B ownership: 4 n x 8 k per thread
  const int nq = t & 31;             // n-quad id
  const int kb = t >> 5;             // k-octet id (0..7)
  const int n0 = bn * 128 + nq * 4;
  const int bidx = n0 / HW_;
  const int rem  = n0 - bidx * HW_;
  const int hh   = rem / W_;
  const int w0   = rem - hh * W_;    // multiple of 4
  const float* xb = x + (size_t)bidx * CIN_ * HW_;

  const ushort_t* wtile = wsw + (size_t)(bm * 4) * 8192;

  uint4  areg[4];
  float4 bmain[8];
  float  bedge[8];

  #define LOAD_A(s)                                                         \
    { const ushort_t* src = wtile + (s) * 8192 + t * 8;                     \
      _Pragma("unroll")                                                     \
      for (int r = 0; r < 4; ++r) areg[r] = *(const uint4*)(src + r * 2048); }

  #define LOAD_B(s)                                                         \
    { _Pragma("unroll")                                                     \
      for (int j = 0; j < 8; ++j) {                                         \
        int c = (s) * 64 + kb * 8 + j;                                      \
        int dx, dy; cdir(c, dx, dy);                                        \
        int h2 = hh - dy;                                                   \
        if ((unsigned)h2 < (unsigned)H_) {                                  \
          const float* row = xb + (size_t)c * HW_ + h2 * W_;                \
          bmain[j] = *(const float4*)(row + w0);                            \
          bedge[j] = (dx == 1) ? ((w0 > 0) ? row[w0 - 1] : 0.f)             \
                   : (dx == -1) ? ((w0 < 52) ? row[w0 + 4] : 0.f) : 0.f;    \
        } else { bmain[j] = make_float4(0.f,0.f,0.f,0.f); bedge[j] = 0.f; } \
      } }

  #define STAGE(buf, s)                                                     \
    { _Pragma("unroll")                                                     \
      for (int r = 0; r < 4; ++r)                                           \
        *(uint4*)&Ab[buf][r * 2048 + t * 8] = areg[r];                      \
      _Pragma("unroll")                                                     \
      for (int i = 0; i < 4; ++i) {                                         \
        int n = nq * 4 + i;                                                 \
        ushort_t kv[8];                                                     \
        _Pragma("unroll")                                                   \
        for (int j = 0; j < 8; ++j) {                                       \
          int c = (s) * 64 + kb * 8 + j;                                    \
          int dx, dy; cdir(c, dx, dy);                                      \
          float v;                                                          \
          if (dx == 0)      v = ((const float*)&bmain[j])[i];               \
          else if (dx == 1) v = (i == 0) ? bedge[j]                         \
                                         : ((const float*)&bmain[j])[i - 1];\
          else              v = (i == 3) ? bedge[j]                         \
                                         : ((const float*)&bmain[j])[i + 1];\
          kv[j] = f2bf(v);                                                  \
        }                                                                   \
        *(uint4*)&Bb[buf][n * 64 + ((kb ^ ((n ^ (n >> 3)) & 7)) << 3)] =    \
            *(uint4*)kv;                                                    \
      } }

  f32x4 acc[4][4];
  #pragma unroll
  for (int i = 0; i < 4; ++i)
    #pragma unroll
    for (int j = 0; j < 4; ++j)
      acc[i][j] = (f32x4){0.f, 0.f, 0.f, 0.f};

  LOAD_A(0);
  LOAD_B(0);

  #pragma unroll
  for (int s = 0; s < 4; ++s) {
    const int buf = s & 1;
    STAGE(buf, s);
    __syncthreads();
    if (s < 3) { LOAD_A(s + 1); LOAD_B(s + 1); }   // prefetch drains during compute
    #pragma unroll
    for (int ks = 0; ks < 2; ++ks) {
      int kb8 = ks * 32 + quad * 8;
      short8 af[4], bfr[4];
      #pragma unroll
      for (int f = 0; f < 4; ++f) {
        int ml = wm * 64 + f * 16 + l15;
        af[f]  = *(const short8*)(&Ab[buf][ml * 64 + (kb8 ^ swz(ml))]);
        int nl = wn * 64 + f * 16 + l15;
        bfr[f] = *(const short8*)(&Bb[buf][nl * 64 + (kb8 ^ swz(nl))]);
      }
      #pragma unroll
      for (int mf = 0; mf < 4; ++mf)
        #pragma unroll
        for (int nf = 0; nf < 4; ++nf)
          acc[mf][nf] = __builtin_amdgcn_mfma_f32_16x16x32_bf16(
              af[mf], bfr[nf], acc[mf][nf], 0, 0, 0);
    }
    // no trailing barrier: next stage writes the other buffer; reuse of this
    // buffer happens only after the next barrier (all waves past compute(s)).
  }

  // ---- epilogue: BN + ReLU + fp32 store ----
  size_t nbase[4];
  #pragma unroll
  for (int nf = 0; nf < 4; ++nf) {
    int ng  = bn * 128 + wn * 64 + nf * 16 + l15;
    int b2  = ng / HW_;
    int hw2 = ng - b2 * HW_;
    nbase[nf] = (size_t)b2 * COUT_ * HW_ + hw2;
  }
  #pragma unroll
  for (int mf = 0; mf < 4; ++mf) {
    int mloc = wm * 64 + mf * 16 + quad * 4;
    int og   = bm * 128 + mloc;
    float inv[4], add[4];
    #pragma unroll
    for (int r = 0; r < 4; ++r) {
      inv[r] = bnp[2 * (og + r)];
      add[r] = bnp[2 * (og + r) + 1];
    }
    size_t obase = (size_t)og * HW_;
    #pragma unroll
    for (int nf = 0; nf < 4; ++nf) {
      #pragma unroll
      for (int r = 0; r < 4; ++r) {
        float v = acc[mf][nf][r] * inv[r] + add[r];
        out[nbase[nf] + obase + (size_t)r * HW_] = fmaxf(v, 0.0f);
      }
    }
  }
}

// ---- fallback (R5, self-contained) if ws is too small ----
__global__ __launch_bounds__(256, 2)
void shiftconv_gemm_fb(const float* __restrict__ x, const float* __restrict__ wgt,
                       const float* __restrict__ gamma, const float* __restrict__ beta,
                       const float* __restrict__ rmean, const float* __restrict__ rvar,
                       float* __restrict__ out) {
  __shared__ ushort_t Alds[128 * 64];
  __shared__ ushort_t Blds[128 * 64];
  __shared__ float bnp[256];
  const int t = threadIdx.x, bn = blockIdx.x, bm = blockIdx.y;
  const int lane = t & 63, wv = t >> 6, wm = wv >> 1, wn = wv & 1;
  const int quad = lane >> 4, l15 = lane & 15;
  if (t < 128) {
    int o = bm * 128 + t;
    float inv = gamma[o] * rsqrtf(rvar[o] + 1e-5f);
    bnp[2 * t] = inv; bnp[2 * t + 1] = beta[o] - rmean[o] * inv;
  }
  const int chunk = t & 15, krow = t >> 4;
  const int nloc0 = chunk * 8, nglob0 = bn * 128 + nloc0;
  const int bidx = nglob0 / HW_, rem = nglob0 - bidx * HW_;
  const int hh = rem / W_, w0 = rem - hh * W_;
  const size_t xb = (size_t)bidx * CIN_ * HW_;
  const int kc = t & 7, am0 = t >> 3;
  f32x4 acc[4][4];
  #pragma unroll
  for (int i = 0; i < 4; ++i)
    #pragma unroll
    for (int j = 0; j < 4; ++j) acc[i][j] = (f32x4){0.f,0.f,0.f,0.f};
  for (int k0 = 0; k0 < CIN_; k0 += 64) {
    #pragma unroll
    for (int p = 0; p < 4; ++p) {
      int m = am0 + 32 * p, o = bm * 128 + m;
      const float* src = wgt + (size_t)o * CIN_ + k0 + kc * 8;
      float4 f0 = *(const float4*)(src); float4 f1 = *(const float4*)(src + 4);
      union { uint4 v; ushort_t s[8]; } pk;
      pk.s[0]=f2bf(f0.x); pk.s[1]=f2bf(f0.y); pk.s[2]=f2bf(f0.z); pk.s[3]=f2bf(f0.w);
      pk.s[4]=f2bf(f1.x); pk.s[5]=f2bf(f1.y); pk.s[6]=f2bf(f1.z); pk.s[7]=f2bf(f1.w);
      *(uint4*)(&Alds[m * 64 + ((kc * 8) ^ swz(m))]) = pk.v;
    }
    #pragma unroll
    for (int p = 0; p < 4; ++p) {
      int kk = krow + 16 * p, c = k0 + kk;
      int dx, dy; cdir(c, dx, dy);
      int h2 = hh - dy;
      float vals[8];
      if ((unsigned)h2 < (unsigned)H_) {
        const float* row = x + xb + (size_t)c * HW_ + h2 * W_;
        float4 a = *(const float4*)(row + w0); float4 b = *(const float4*)(row + w0 + 4);
        float sArr[8] = {a.x,a.y,a.z,a.w,b.x,b.y,b.z,b.w};
        if (dx == 0) { for (int i = 0; i < 8; ++i) vals[i] = sArr[i]; }
        else if (dx == 1) { for (int i = 7; i >= 1; --i) vals[i] = sArr[i-1];
                            vals[0] = (w0 > 0) ? row[w0 - 1] : 0.f; }
        else { for (int i = 0; i < 7; ++i) vals[i] = sArr[i+1];
               vals[7] = (w0 + 8 < W_) ? row[w0 + 8] : 0.f; }
      } else { for (int i = 0; i < 8; ++i) vals[i] = 0.f; }
      #pragma unroll
      for (int i = 0; i < 8; ++i) {
        int nl = nloc0 + i;
        Blds[nl * 64 + (kk ^ swz(nl))] = f2bf(vals[i]);
      }
    }
    __syncthreads();
    #pragma unroll
    for (int ks = 0; ks < 2; ++ks) {
      int kb8 = ks * 32 + quad * 8;
      short8 af[4], bfr[4];
      #pragma unroll
      for (int f = 0; f < 4; ++f) {
        int ml = wm * 64 + f * 16 + l15;
        af[f] = *(const short8*)(&Alds[ml * 64 + (kb8 ^ swz(ml))]);
        int nl = wn * 64 + f * 16 + l15;
        bfr[f] = *(const short8*)(&Blds[nl * 64 + (kb8 ^ swz(nl))]);
      }
      #pragma unroll
      for (int mf = 0; mf < 4; ++mf)
        #pragma unroll
        for (int nf = 0; nf < 4; ++nf)
          acc[mf][nf] = __builtin_amdgcn_mfma_f32_16x16x32_bf16(af[mf], bfr[nf], acc[mf][nf], 0, 0, 0);
    }
    __syncthreads();
  }
  size_t nbase[4];
  #pragma unroll
  for (int nf = 0; nf < 4; ++nf) {
    int ng = bn * 128 + wn * 64 + nf * 16 + l15;
    int b2 = ng / HW_, hw2 = ng - b2 * HW_;
    nbase[nf] = (size_t)b2 * COUT_ * HW_ + hw2;
  }
  #pragma unroll
  for (int mf = 0; mf < 4; ++mf) {
    int mloc = wm * 64 + mf * 16 + quad * 4;
    float inv[4], add[4];
    #pragma unroll
    for (int r = 0; r < 4; ++r) { inv[r] = bnp[2*(mloc+r)]; add[r] = bnp[2*(mloc+r)+1]; }
    size_t obase = (size_t)(bm * 128 + mloc) * HW_;
    #pragma unroll
    for (int nf = 0; nf < 4; ++nf)
      #pragma unroll
      for (int r = 0; r < 4; ++r) {
        float v = acc[mf][nf][r] * inv[r] + add[r];
        out[nbase[nf] + obase + (size_t)r * HW_] = fmaxf(v, 0.0f);
      }
  }
}

extern "C" void kernel_launch(void* const* d_in, const int* in_sizes, int n_in,
                              void* d_out, int out_size, void* d_ws, size_t ws_size,
                              hipStream_t stream) {
  const float* x     = (const float*)d_in[0];
  const float* wgt   = (const float*)d_in[1];
  const float* gamma = (const float*)d_in[2];
  const float* beta  = (const float*)d_in[3];
  const float* rmean = (const float*)d_in[4];
  const float* rvar  = (const float*)d_in[5];
  float* out = (float*)d_out;
  dim3 grid(784, 2);
  if (ws_size >= (size_t)(131072 + 2048)) {
    ushort_t* wsw = (ushort_t*)d_ws;
    float* bnp = (float*)((char*)d_ws + 131072);
    prep_kernel<<<256, 256, 0, stream>>>(wgt, gamma, beta, rmean, rvar, wsw, bnp);
    shiftconv_mfma<<<grid, dim3(256), 0, stream>>>(x, wsw, bnp, out);
  } else {
    shiftconv_gemm_fb<<<grid, dim3(256), 0, stream>>>(x, wgt, gamma, beta, rmean, rvar, out);
  }
}